// Round 8
// baseline (168.539 us; speedup 1.0000x reference)
//
#include <hip/hip_runtime.h>

#define M1 81
#define MSZ 80
#define NEL (M1 * M1)          // 6561
#define NTW ((NEL + 31) / 32)  // 206 words of target bits
#define NACC 12
#define BIGKC 1.0e30f

// accumulator indices:
// 0 target_num, 1 n_pre, 2 n_next, 3 n_union,
// 4 s_pre, 5 s_next, 6 s_all, 7 s_sim,
// 8 s_acc_pre, 9 s_acc_next, 10 n_mpre, 11 n_mnext

__global__ __launch_bounds__(512, 8) void sst_main(
    const float* __restrict__ input,
    const int* __restrict__ target,
    const int* __restrict__ mask0,
    const int* __restrict__ mask1,
    float* __restrict__ out_idx,   // d_out + 7, [slices*80] floats
    float* __restrict__ part,      // SoA: part[k*slices + slice]
    int slices)
{
    __shared__ float s_x[NEL];          // x during staging, e=exp(z) after sweep A
    __shared__ unsigned s_tb[NTW];      // target bits, row-major
    __shared__ float s_m0[M1], s_m1[M1];
    __shared__ float s_kc[M1];          // log(csum) (1e30 sentinel @80)
    __shared__ float s_invc[M1];        // 1/csum (0.0 sentinel @80)
    __shared__ float s_pA[486];         // sweepA csum partials
    __shared__ float s_pC[480];         // sweepB rsum partials
    __shared__ float s_pV[486];         // argmax value partials (A: col, C: row)
    __shared__ unsigned char s_pI[486]; // argmax index partials
    __shared__ unsigned char s_pT[486]; // first-target partials (127 = none)
    __shared__ unsigned s_m1w[4];       // m1 bitmask (bit c = mask1[c] != 0)
    __shared__ float s_wv[8][NACC];

    const int tid   = threadIdx.x;
    const int lane  = tid & 63;
    const int w     = tid >> 6;
    const int slice = blockIdx.x;
    const size_t base = (size_t)slice * NEL;

    if (tid < M1) s_m0[tid] = (float)mask0[slice * M1 + tid];
    else if (tid >= 128 && tid < 128 + M1) s_m1[tid - 128] = (float)mask1[slice * M1 + (tid - 128)];

    float a[NACC];
#pragma unroll
    for (int k = 0; k < NACC; ++k) a[k] = 0.0f;

    // ---- staging: coalesced input + ballot-packed target bits ----
    for (int i = tid; i < NEL; i += 512) {
        s_x[i] = input[base + i];
        unsigned long long m = __ballot(target[base + i] != 0);
        if (lane == 0) {
            const int w2 = (i >> 5) & ~1;
            s_tb[w2] = (unsigned)m;
            if (w2 + 1 < NTW) s_tb[w2 + 1] = (unsigned)(m >> 32);
        }
    }
    __syncthreads();   // B1

    // m1 bit windows (consumed in sweep C, after B3)
    if (w == 0) {
        const unsigned long long m = __ballot(s_m1[lane] != 0.0f);
        if (lane == 0) { s_m1w[0] = (unsigned)m; s_m1w[1] = (unsigned)(m >> 32); }
    } else if (w == 1) {
        float v = 0.0f;
        if (lane < 17) v = s_m1[64 + lane];
        const unsigned long long m = __ballot(v != 0.0f);
        if (lane == 0) { s_m1w[2] = (unsigned)m; s_m1w[3] = 0u; }
    }

    // ---- sweep A: columns (81 x 6 threads); store e = exp(m1c*m0r*x) in place ----
    if (tid < 486) {
        const int c = tid / 6, j = tid - 6 * (tid / 6);
        const int r0 = j * 13 + ((j < 3) ? j : 3);
        const int len = (j < 3) ? 14 : 13;
        const float m1c = s_m1[c];
        const float mcol = (c == MSZ) ? 0.0f : m1c;  // next-mask zeroes col 80
        float cs = 0.0f, bv = -1.0f;
        int bi = r0, ct = 127;
        for (int i = 0; i < len; ++i) {
            const int r = r0 + i;
            const int idx = r * M1 + c;
            const float m0r = s_m0[r];
            const float z = m1c * m0r * s_x[idx];
            const float e = __expf(z);
            s_x[idx] = e;                     // same-thread overwrite: race-free
            cs += e;
            if (e > bv) { bv = e; bi = r; }   // first-max (e-domain, ascending r)
            const unsigned tb = (s_tb[idx >> 5] >> (idx & 31)) & 1u;
            if (ct == 127 && tb != 0u && (mcol * m0r) != 0.0f) ct = r;
        }
        s_pA[tid] = cs; s_pV[tid] = bv;
        s_pI[tid] = (unsigned char)bi; s_pT[tid] = (unsigned char)ct;
    }
    __syncthreads();   // B2

    // ---- sweep B (rows 0..79, tids 0..479: pure adds) | colmerge + popc (480..511) ----
    if (tid < 480) {
        const int r = tid / 6, j = tid - 6 * (tid / 6);
        const int c0 = j * 13 + ((j < 3) ? j : 3);
        const int len = (j < 3) ? 14 : 13;
        const int rb = r * M1 + c0;
        float rs = 0.0f;
        for (int i = 0; i < len; ++i) rs += s_x[rb + i];
        s_pC[tid] = rs;
    } else {
        const int u = tid - 480;
        for (int c = u; c < M1; c += 32) {
            if (c < MSZ) {
                const int b = 6 * c;
                float cs = 0.0f;
#pragma unroll
                for (int k = 0; k < 6; ++k) cs += s_pA[b + k];
                float bv = s_pV[b]; int bi = s_pI[b];
#pragma unroll
                for (int k = 1; k < 6; ++k) {
                    const float v = s_pV[b + k];
                    if (v > bv) { bv = v; bi = s_pI[b + k]; }  // ascending: first-max
                }
                int ct = 127;
#pragma unroll
                for (int k = 0; k < 6; ++k) ct = min(ct, (int)s_pT[b + k]);
                if (ct == 127) ct = 0;
                s_kc[c] = __logf(cs);
                s_invc[c] = 1.0f / cs;
                const float m1c = s_m1[c];
                a[9]  += (bi == ct) ? m1c : 0.0f;
                a[11] += m1c;
            } else {
                s_kc[c] = BIGKC;     // sparse path: min(lr,kc)=lr at col 80
                s_invc[c] = 0.0f;    // argmax path: val = e*invr at col 80
            }
        }
        // target_num: popc over packed bits (stray bits are 0 by ballot masking)
        float tn = 0.0f;
        for (int wd = u; wd < NTW; wd += 32) tn += (float)__popc(s_tb[wd]);
        a[0] += tn;
    }
    __syncthreads();   // B3

    // ---- sweep C: rows 0..79 (tids 0..479) + row-80 next-terms (480..485) ----
    if (tid < 480) {
        const int r = tid / 6, j = tid - 6 * (tid / 6);
        const int c0 = j * 13 + ((j < 3) ? j : 3);
        const int len = (j < 3) ? 14 : 13;
        const int rb = r * M1;
        const int pb = 6 * r;
        const float rs = s_pC[pb] + s_pC[pb + 1] + s_pC[pb + 2]
                       + s_pC[pb + 3] + s_pC[pb + 4] + s_pC[pb + 5];
        const float lr = __logf(rs), invr = 1.0f / rs;
        const float m0f = s_m0[r];

        // bit window: t & m1 & m0p over cols [c0, c0+len)
        const int bp = rb + c0;
        const unsigned long long tw64 =
            ((unsigned long long)s_tb[(bp >> 5) + 1] << 32) | s_tb[bp >> 5];
        const int mp0 = c0 >> 5;
        const unsigned long long mw64 =
            ((unsigned long long)s_m1w[mp0 + 1] << 32) | s_m1w[mp0];
        const unsigned lenmask = (1u << len) - 1u;
        unsigned wb = (unsigned)(tw64 >> (bp & 31)) & (unsigned)(mw64 >> (c0 & 31)) & lenmask;
        if (m0f == 0.0f) wb = 0u;

        const unsigned w3 = (j == 5) ? (wb & 0x0FFFu) : wb;  // drop c=80 bit
        a[1] += (float)__popc(wb);   // n_pre
        a[2] += (float)__popc(w3);   // n_next (rows<80 part)
        a[3] += (float)__popc(w3);   // n_union
        const int ti = wb ? (c0 + __ffs(wb) - 1) : 127;

        // unconditional: row argmax of input_all = e * max(invr, invc)
        float bv = -3.402823466e38f; int bi = c0;
        for (int i = 0; i < len; ++i) {
            const int c = c0 + i;
            const float val = s_x[rb + c] * fmaxf(invr, s_invc[c]);
            if (val > bv) { bv = val; bi = c; }   // strict >, ascending: first-max
        }
        // sparse t-terms (z recovered via log; e already in LDS)
        unsigned wl = wb;
        while (wl) {
            const int b = __ffs(wl) - 1; wl &= wl - 1u;
            const int c = c0 + b;
            const float e = s_x[rb + c];
            const float z = __logf(e);
            const float kc = s_kc[c];
            a[4] += lr - z;                              // s_pre
            a[6] += fminf(lr, kc) - z;                   // s_all (c=80: min=lr)
            const bool c80 = (c == MSZ);
            a[5] += c80 ? 0.0f : (kc - z);               // s_next (rows<80 part)
            const float es = c80 ? 0.0f : e;
            a[7] = fmaf(es, fabsf(s_invc[c] - invr), a[7]);  // sim (union excl c80)
        }
        s_pV[tid] = bv; s_pI[tid] = (unsigned char)bi; s_pT[tid] = (unsigned char)ti;
    } else if (tid < 486) {
        // row 80: only n_next / s_next terms survive (next-mask keeps row 80)
        const int j = tid - 480;
        const int c0 = j * 13 + ((j < 3) ? j : 3);
        const int len = (j < 3) ? 14 : 13;
        const int rb = MSZ * M1;
        const float m80 = s_m0[MSZ];
        const int bp = rb + c0;
        const unsigned long long tw64 =
            ((unsigned long long)s_tb[(bp >> 5) + 1] << 32) | s_tb[bp >> 5];
        const int mp0 = c0 >> 5;
        const unsigned long long mw64 =
            ((unsigned long long)s_m1w[mp0 + 1] << 32) | s_m1w[mp0];
        const unsigned lenmask = (1u << len) - 1u;
        unsigned wb = (unsigned)(tw64 >> (bp & 31)) & (unsigned)(mw64 >> (c0 & 31)) & lenmask;
        if (m80 == 0.0f) wb = 0u;
        if (j == 5) wb &= 0x0FFFu;                       // next-mask zeroes col 80
        a[2] += (float)__popc(wb);
        while (wb) {
            const int b = __ffs(wb) - 1; wb &= wb - 1u;
            const int c = c0 + b;
            a[5] += s_kc[c] - __logf(s_x[rb + c]);
        }
    }
    __syncthreads();   // B4

    if (tid < MSZ) {   // merge row argmax + accuracy_pre
        const int b = 6 * tid;
        float bv = s_pV[b]; int bi = s_pI[b];
#pragma unroll
        for (int k = 1; k < 6; ++k) {
            const float v = s_pV[b + k];
            if (v > bv) { bv = v; bi = s_pI[b + k]; }
        }
        int ti = 127;
#pragma unroll
        for (int k = 0; k < 6; ++k) ti = min(ti, (int)s_pT[b + k]);
        if (ti == 127) ti = 0;
        out_idx[(size_t)slice * MSZ + tid] = (float)bi;
        const float m0f = s_m0[tid];
        a[8]  += (bi == ti) ? m0f : 0.0f;
        a[10] += m0f;
    }

    // ---- block reduce: wave shuffle -> LDS -> SoA partials ----
#pragma unroll
    for (int k = 0; k < NACC; ++k) {
        float v = a[k];
        for (int off = 32; off > 0; off >>= 1) v += __shfl_down(v, off);
        if (lane == 0) s_wv[w][k] = v;
    }
    __syncthreads();   // B5
    if (tid < NACC) {
        float s = 0.0f;
#pragma unroll
        for (int ww = 0; ww < 8; ++ww) s += s_wv[ww][tid];
        part[(size_t)tid * slices + slice] = s;
    }
}

__global__ __launch_bounds__(256) void sst_final(
    const float* __restrict__ part, int slices, float* __restrict__ out)
{
    __shared__ double s_part[4][NACC];
    const int tid = threadIdx.x;
    double l[NACC];
#pragma unroll
    for (int k = 0; k < NACC; ++k) l[k] = 0.0;
    for (int s = tid; s < slices; s += 256) {
#pragma unroll
        for (int k = 0; k < NACC; ++k) l[k] += (double)part[(size_t)k * slices + s];
    }
#pragma unroll
    for (int k = 0; k < NACC; ++k) {
        double v = l[k];
        for (int off = 32; off > 0; off >>= 1) v += __shfl_down(v, off);
        if ((tid & 63) == 0) s_part[tid >> 6][k] = v;
    }
    __syncthreads();
    if (tid == 0) {
        double g[NACC];
#pragma unroll
        for (int k = 0; k < NACC; ++k)
            g[k] = s_part[0][k] + s_part[1][k] + s_part[2][k] + s_part[3][k];
        const double tnum = g[0], npre = g[1], nnext = g[2], nunion = g[3];
        const double spre = g[4], snext = g[5], sall = g[6], ssim = g[7];
        const double accp = g[8], accn = g[9], nmp = g[10], nmn = g[11];
        const double loss_pre  = (npre > 0.0) ? spre / npre : spre;
        const double loss_next = (nnext > 0.0) ? snext / nnext : snext;
        const double loss      = (npre > 0.0 && nnext > 0.0) ? sall / npre : sall;
        const double loss_sim  = (nunion > 0.0) ? ssim / tnum : ssim;
        const double total = (loss_pre + loss_next + loss + loss_sim) * 0.25;
        const double ap = (nmp > 0.0) ? accp / nmp : accp + 1.0;
        const double an = (nmn > 0.0) ? accn / nmn : accn + 1.0;
        out[0] = (float)loss_pre;
        out[1] = (float)loss_next;
        out[2] = (float)loss_sim;
        out[3] = (float)total;
        out[4] = (float)ap;
        out[5] = (float)an;
        out[6] = (float)((ap + an) * 0.5);
    }
}

extern "C" void kernel_launch(void* const* d_in, const int* in_sizes, int n_in,
                              void* d_out, int out_size, void* d_ws, size_t ws_size,
                              hipStream_t stream) {
    const float* input  = (const float*)d_in[0];
    const int*   target = (const int*)d_in[1];
    const int*   mask0  = (const int*)d_in[2];
    const int*   mask1  = (const int*)d_in[3];
    float* out = (float*)d_out;
    float* part = (float*)d_ws;   // NACC * slices floats, SoA

    const int slices = in_sizes[0] / NEL;  // B*C = 2048

    sst_main<<<slices, 512, 0, stream>>>(input, target, mask0, mask1, out + 7, part, slices);
    sst_final<<<1, 256, 0, stream>>>(part, slices, out);
}